// Round 5
// baseline (728.502 us; speedup 1.0000x reference)
//
#include <hip/hip_runtime.h>

#define EPSV 1e-5f

typedef float f4 __attribute__((ext_vector_type(4)));
typedef float f2 __attribute__((ext_vector_type(2)));

// Problem constants (match setup_inputs)
#define B   16
#define CIN 3
#define C1  64
#define C   256
#define H   128
#define W   128
#define K   5
#define KK  25
#define FSTR 28            // padded filter stride (16B-aligned f4 loads)

// ---------------------------------------------------------------------------
// Kernel 1: Conv2d(3->64,3x3,zero-pad 1) + bias + BN(eval) + ReLU -> partial
// sums for global avg pool. Grid 1024 blocks x 128 thr. (unchanged)
// ---------------------------------------------------------------------------
#define R1   8
#define WS1  32
#define TW1  36

__global__ __launch_bounds__(128) void k1_conv_pool(
    const float* __restrict__ raw, const float* __restrict__ wconv,
    const float* __restrict__ bconv, const float* __restrict__ g1,
    const float* __restrict__ be1, const float* __restrict__ m1,
    const float* __restrict__ v1, float* __restrict__ partial)
{
  const int bid   = blockIdx.x;
  const int b     = bid >> 6;
  const int chunk = (bid >> 2) & 15;
  const int wh    = bid & 3;
  const int tid   = threadIdx.x;

  __shared__ __align__(16) float t[CIN][R1 + 2][TW1];
  const float* rawb = raw + (size_t)b * CIN * H * W;
  for (int i = tid; i < CIN * (R1 + 2) * 34; i += 128) {
    int ic  = i / ((R1 + 2) * 34);
    int rem = i - ic * (R1 + 2) * 34;
    int r   = rem / 34;
    int cc  = rem - r * 34;
    int gr  = chunk * R1 + r - 1;
    int gc  = wh * WS1 + cc - 1;
    float val = 0.f;
    if ((unsigned)gr < H && (unsigned)gc < W)
      val = rawb[ic * H * W + gr * W + gc];
    t[ic][r][cc] = val;
  }
  __syncthreads();

  const int rp  = tid >> 5;
  const int grp = tid & 31;
  float wt[2][27], A[2], Bc[2];
#pragma unroll
  for (int g = 0; g < 2; ++g) {
    int c = grp * 2 + g;
#pragma unroll
    for (int k = 0; k < 27; ++k) wt[g][k] = wconv[c * 27 + k];
    float sc = g1[c] * rsqrtf(v1[c] + EPSV);
    A[g]  = sc;
    Bc[g] = (bconv[c] - m1[c]) * sc + be1[c];
  }

  f4 cur[CIN][4], nxt[CIN][4];
#pragma unroll
  for (int ic = 0; ic < CIN; ++ic)
#pragma unroll
    for (int r = 0; r < 4; ++r) cur[ic][r] = *(const f4*)&t[ic][2 * rp + r][0];

  float acc0 = 0.f, acc1 = 0.f;
#pragma unroll
  for (int j = 0; j < 8; ++j) {
#pragma unroll
    for (int ic = 0; ic < CIN; ++ic)
#pragma unroll
      for (int r = 0; r < 4; ++r) nxt[ic][r] = *(const f4*)&t[ic][2 * rp + r][4 * j + 4];

    float v[2][2][4];
#pragma unroll
    for (int q = 0; q < 2; ++q)
#pragma unroll
      for (int g = 0; g < 2; ++g)
#pragma unroll
        for (int p = 0; p < 4; ++p) v[q][g][p] = 0.f;

#pragma unroll
    for (int ic = 0; ic < CIN; ++ic) {
#pragma unroll
      for (int q = 0; q < 2; ++q) {
#pragma unroll
        for (int kh = 0; kh < 3; ++kh) {
          f4 a  = cur[ic][q + kh];
          f4 bb = nxt[ic][q + kh];
#pragma unroll
          for (int p = 0; p < 4; ++p) {
#pragma unroll
            for (int kw = 0; kw < 3; ++kw) {
              float e = (p + kw < 4) ? a[p + kw] : bb[p + kw - 4];
              v[q][0][p] += e * wt[0][ic * 9 + kh * 3 + kw];
              v[q][1][p] += e * wt[1][ic * 9 + kh * 3 + kw];
            }
          }
        }
      }
    }
#pragma unroll
    for (int q = 0; q < 2; ++q)
#pragma unroll
      for (int p = 0; p < 4; ++p) {
        acc0 += fmaxf(v[q][0][p] * A[0] + Bc[0], 0.f);
        acc1 += fmaxf(v[q][1][p] * A[1] + Bc[1], 0.f);
      }
#pragma unroll
    for (int ic = 0; ic < CIN; ++ic)
#pragma unroll
      for (int r = 0; r < 4; ++r) cur[ic][r] = nxt[ic][r];
  }

  __shared__ float red[4][C1];
  red[rp][grp * 2]     = acc0;
  red[rp][grp * 2 + 1] = acc1;
  __syncthreads();
  if (tid < C1) {
    float s = red[0][tid] + red[1][tid] + red[2][tid] + red[3][tid];
    partial[((size_t)((b * 16 + chunk) * 4 + wh)) * C1 + tid] = s;
  }
}

// ---------------------------------------------------------------------------
// Kernel 2: pool mean -> dense + BN -> softmax over C. Writes padded stride 28.
// (unchanged)
// ---------------------------------------------------------------------------
#define NCH 64

__global__ __launch_bounds__(256) void k2_filter(
    const float* __restrict__ partial, const float* __restrict__ wf,
    const float* __restrict__ bf, const float* __restrict__ g2,
    const float* __restrict__ be2, const float* __restrict__ m2,
    const float* __restrict__ v2, float* __restrict__ filt)
{
  const int b  = blockIdx.x / KK;
  const int kk = blockIdx.x - b * KK;
  const int c  = threadIdx.x;

  __shared__ float feat[C1];
  if (c < C1) {
    float s = 0.f;
#pragma unroll
    for (int ch = 0; ch < NCH; ++ch)
      s += partial[((size_t)b * NCH + ch) * C1 + c];
    feat[c] = s * (1.f / (H * W));
  }
  __syncthreads();

  const int idx = c * KK + kk;
  float v = bf[idx];
  const float* wr = wf + (size_t)idx * C1;
#pragma unroll
  for (int j = 0; j < C1; ++j) v += feat[j] * wr[j];
  v = (v - m2[idx]) * (g2[idx] * rsqrtf(v2[idx] + EPSV)) + be2[idx];

  __shared__ float red[256];
  red[c] = v;
  __syncthreads();
#pragma unroll
  for (int s = 128; s > 0; s >>= 1) {
    if (c < s) red[c] = fmaxf(red[c], red[c + s]);
    __syncthreads();
  }
  float mx = red[0];
  __syncthreads();
  float e = expf(v - mx);
  red[c] = e;
  __syncthreads();
#pragma unroll
  for (int s = 128; s > 0; s >>= 1) {
    if (c < s) red[c] += red[c + s];
    __syncthreads();
  }
  filt[((size_t)b * C + c) * FSTR + kk] = e / red[0];
}

// ---------------------------------------------------------------------------
// Kernel 3: per-sample dynamic depthwise 5x5 conv, reflect pad 2.
// LDS-free, barrier-free column-strip design: each thread owns 4 output cols
// x 64 rows, sliding 5-row register window, 2 aligned f4 loads per row
// (neighbor-lane overlap -> L1 hits), depth-1 prefetch, NT f2 stores.
// Lane g=31 handles the 4 reflect-edge cols (126,127,0,1) from the same two
// aligned windows via 4 cndmasks/row. 1024 blocks x 256 thr = 4 blocks/CU.
// ---------------------------------------------------------------------------

// load input row rr (reflect-mapped) -> Mv, Rv
#define LOADRC(rr, Mv, Rv)                                                    \
  {                                                                           \
    int _rr = (rr);                                                           \
    int _gr = _rr < 0 ? -_rr : (_rr >= H ? 2 * H - 2 - _rr : _rr);            \
    Mv = *(const f4*)&xp[_gr * W + mcol];                                     \
    Rv = *(const f4*)&xp[_gr * W + rcol];                                     \
  }

// place loaded row into window slot s (builds wa/wb with edge remap)
#define PLACE(s, Mv, Rv)                                                      \
  {                                                                           \
    wa[s][0] = Mv[0]; wa[s][1] = Mv[1]; wa[s][2] = Mv[2]; wa[s][3] = Mv[3];   \
    wa[s][4] = edge ? Mv[2] : Rv[0];                                          \
    wa[s][5] = edge ? Mv[1] : Rv[1];                                          \
    wb[s][0] = edge ? Rv[2] : Mv[2];                                          \
    wb[s][1] = edge ? Rv[1] : Mv[3];                                          \
    wb[s][2] = Rv[0]; wb[s][3] = Rv[1]; wb[s][4] = Rv[2]; wb[s][5] = Rv[3];   \
  }

__global__ __launch_bounds__(256, 4) void k3_dwconv(
    const float* __restrict__ x, const float* __restrict__ filt,
    float* __restrict__ out)
{
  const int tid   = threadIdx.x;
  const int g     = tid & 31;          // column group
  const int half  = (tid >> 5) & 1;    // row half (0: rows 0.., 1: rows 64..)
  const int psub  = tid >> 6;          // plane within block (0..3)
  const int plane = blockIdx.x * 4 + psub;

  const float* xp = x   + (size_t)plane * H * W;
  float*       op = out + (size_t)plane * H * W;
  const float* fp = filt + (size_t)plane * FSTR;

  f4 fv[7];
#pragma unroll
  for (int i = 0; i < 7; ++i) fv[i] = *(const f4*)&fp[i << 2];

  const bool edge  = (g == 31);
  const int  mcol  = g << 2;                   // 124 for edge
  const int  rcol  = (mcol + 4) & 127;         // 0 for edge
  const int  ocolA = edge ? 126 : mcol + 2;    // f2 store col (outputs p=0,1)
  const int  ocolB = edge ? 0   : mcol + 4;    // f2 store col (outputs p=2,3)
  const int  r0    = half << 6;                // output rows r0 .. r0+64

  float wa[5][6], wb[5][6];
  f4 Mp, Rp;

  // prime slots 0..3 with input rows r0-2 .. r0+1
  {
    f4 M0, R0;
    LOADRC(r0 - 2, M0, R0) PLACE(0, M0, R0)
    LOADRC(r0 - 1, M0, R0) PLACE(1, M0, R0)
    LOADRC(r0 + 0, M0, R0) PLACE(2, M0, R0)
    LOADRC(r0 + 1, M0, R0) PLACE(3, M0, R0)
  }
  LOADRC(r0 + 2, Mp, Rp)   // pending row for ro=0

  // 13 x 5 = 65 output rows; row r0+64 double-computed (bitwise identical) or
  // masked at the bottom edge (r0+64 == 128).
  for (int t = 0; t < 13; ++t) {
#pragma unroll
    for (int u = 0; u < 5; ++u) {
      const int ro  = t * 5 + u;
      const int sin = (u + 4) % 5;           // slot for incoming row ro+2
      PLACE(sin, Mp, Rp)
      LOADRC(r0 + ro + 3, Mp, Rp)            // depth-1 prefetch

      float a0 = 0.f, a1 = 0.f, a2 = 0.f, a3 = 0.f;
#pragma unroll
      for (int ki = 0; ki < 5; ++ki) {
        const int s = (u + ki) % 5;          // slot holding input row ro-2+ki
#pragma unroll
        for (int j = 0; j < 5; ++j) {
          const int kq = ki * 5 + j;
          const float fk = fv[kq >> 2][kq & 3];
          a0 += wa[s][j]     * fk;
          a1 += wa[s][1 + j] * fk;
          a2 += wb[s][j]     * fk;
          a3 += wb[s][1 + j] * fk;
        }
      }
      const int orow = r0 + ro;
      if (orow < H) {
        f2 vA = {a0, a1};
        f2 vB = {a2, a3};
        __builtin_nontemporal_store(vA, (f2*)&op[orow * W + ocolA]);
        __builtin_nontemporal_store(vB, (f2*)&op[orow * W + ocolB]);
      }
    }
  }
}

// ---------------------------------------------------------------------------
extern "C" void kernel_launch(void* const* d_in, const int* in_sizes, int n_in,
                              void* d_out, int out_size, void* d_ws, size_t ws_size,
                              hipStream_t stream) {
  const float* x_feat = (const float*)d_in[0];
  const float* raw    = (const float*)d_in[1];
  const float* wconv  = (const float*)d_in[2];
  const float* bconv  = (const float*)d_in[3];
  const float* g1     = (const float*)d_in[4];
  const float* be1    = (const float*)d_in[5];
  const float* m1     = (const float*)d_in[6];
  const float* v1     = (const float*)d_in[7];
  const float* wf     = (const float*)d_in[8];
  const float* bf     = (const float*)d_in[9];
  const float* g2     = (const float*)d_in[10];
  const float* be2    = (const float*)d_in[11];
  const float* m2     = (const float*)d_in[12];
  const float* v2     = (const float*)d_in[13];
  float* out = (float*)d_out;

  float* partial = (float*)d_ws;                    // B*NCH*C1 floats
  float* filt    = partial + B * NCH * C1;          // B*C*FSTR floats

  k1_conv_pool<<<B * 16 * 4, 128, 0, stream>>>(raw, wconv, bconv, g1, be1, m1, v1, partial);
  k2_filter  <<<B * KK, 256, 0, stream>>>(partial, wf, bf, g2, be2, m2, v2, filt);
  k3_dwconv  <<<B * C / 4, 256, 0, stream>>>(x_feat, filt, out);
}

// Round 6
// 127.040 us; speedup vs baseline: 5.7344x; 5.7344x over previous
//
#include <hip/hip_runtime.h>

#define EPSV 1e-5f

typedef float f4 __attribute__((ext_vector_type(4)));
typedef float f2 __attribute__((ext_vector_type(2)));

// Problem constants (match setup_inputs)
#define B   16
#define CIN 3
#define C1  64
#define C   256
#define H   128
#define W   128
#define K   5
#define KK  25
#define FSTR 28            // padded filter stride (16B-aligned f4 loads)

// ---------------------------------------------------------------------------
// Kernel 1: Conv2d(3->64,3x3,zero-pad 1) + bias + BN(eval) + ReLU -> partial
// sums for global avg pool. Grid 1024 blocks x 128 thr. (unchanged)
// ---------------------------------------------------------------------------
#define R1   8
#define WS1  32
#define TW1  36

__global__ __launch_bounds__(128) void k1_conv_pool(
    const float* __restrict__ raw, const float* __restrict__ wconv,
    const float* __restrict__ bconv, const float* __restrict__ g1,
    const float* __restrict__ be1, const float* __restrict__ m1,
    const float* __restrict__ v1, float* __restrict__ partial)
{
  const int bid   = blockIdx.x;
  const int b     = bid >> 6;
  const int chunk = (bid >> 2) & 15;
  const int wh    = bid & 3;
  const int tid   = threadIdx.x;

  __shared__ __align__(16) float t[CIN][R1 + 2][TW1];
  const float* rawb = raw + (size_t)b * CIN * H * W;
  for (int i = tid; i < CIN * (R1 + 2) * 34; i += 128) {
    int ic  = i / ((R1 + 2) * 34);
    int rem = i - ic * (R1 + 2) * 34;
    int r   = rem / 34;
    int cc  = rem - r * 34;
    int gr  = chunk * R1 + r - 1;
    int gc  = wh * WS1 + cc - 1;
    float val = 0.f;
    if ((unsigned)gr < H && (unsigned)gc < W)
      val = rawb[ic * H * W + gr * W + gc];
    t[ic][r][cc] = val;
  }
  __syncthreads();

  const int rp  = tid >> 5;
  const int grp = tid & 31;
  float wt[2][27], A[2], Bc[2];
#pragma unroll
  for (int g = 0; g < 2; ++g) {
    int c = grp * 2 + g;
#pragma unroll
    for (int k = 0; k < 27; ++k) wt[g][k] = wconv[c * 27 + k];
    float sc = g1[c] * rsqrtf(v1[c] + EPSV);
    A[g]  = sc;
    Bc[g] = (bconv[c] - m1[c]) * sc + be1[c];
  }

  f4 cur[CIN][4], nxt[CIN][4];
#pragma unroll
  for (int ic = 0; ic < CIN; ++ic)
#pragma unroll
    for (int r = 0; r < 4; ++r) cur[ic][r] = *(const f4*)&t[ic][2 * rp + r][0];

  float acc0 = 0.f, acc1 = 0.f;
#pragma unroll
  for (int j = 0; j < 8; ++j) {
#pragma unroll
    for (int ic = 0; ic < CIN; ++ic)
#pragma unroll
      for (int r = 0; r < 4; ++r) nxt[ic][r] = *(const f4*)&t[ic][2 * rp + r][4 * j + 4];

    float v[2][2][4];
#pragma unroll
    for (int q = 0; q < 2; ++q)
#pragma unroll
      for (int g = 0; g < 2; ++g)
#pragma unroll
        for (int p = 0; p < 4; ++p) v[q][g][p] = 0.f;

#pragma unroll
    for (int ic = 0; ic < CIN; ++ic) {
#pragma unroll
      for (int q = 0; q < 2; ++q) {
#pragma unroll
        for (int kh = 0; kh < 3; ++kh) {
          f4 a  = cur[ic][q + kh];
          f4 bb = nxt[ic][q + kh];
#pragma unroll
          for (int p = 0; p < 4; ++p) {
#pragma unroll
            for (int kw = 0; kw < 3; ++kw) {
              float e = (p + kw < 4) ? a[p + kw] : bb[p + kw - 4];
              v[q][0][p] += e * wt[0][ic * 9 + kh * 3 + kw];
              v[q][1][p] += e * wt[1][ic * 9 + kh * 3 + kw];
            }
          }
        }
      }
    }
#pragma unroll
    for (int q = 0; q < 2; ++q)
#pragma unroll
      for (int p = 0; p < 4; ++p) {
        acc0 += fmaxf(v[q][0][p] * A[0] + Bc[0], 0.f);
        acc1 += fmaxf(v[q][1][p] * A[1] + Bc[1], 0.f);
      }
#pragma unroll
    for (int ic = 0; ic < CIN; ++ic)
#pragma unroll
      for (int r = 0; r < 4; ++r) cur[ic][r] = nxt[ic][r];
  }

  __shared__ float red[4][C1];
  red[rp][grp * 2]     = acc0;
  red[rp][grp * 2 + 1] = acc1;
  __syncthreads();
  if (tid < C1) {
    float s = red[0][tid] + red[1][tid] + red[2][tid] + red[3][tid];
    partial[((size_t)((b * 16 + chunk) * 4 + wh)) * C1 + tid] = s;
  }
}

// ---------------------------------------------------------------------------
// Kernel 2: pool mean -> dense + BN -> softmax over C. Writes padded stride 28.
// (unchanged)
// ---------------------------------------------------------------------------
#define NCH 64

__global__ __launch_bounds__(256) void k2_filter(
    const float* __restrict__ partial, const float* __restrict__ wf,
    const float* __restrict__ bf, const float* __restrict__ g2,
    const float* __restrict__ be2, const float* __restrict__ m2,
    const float* __restrict__ v2, float* __restrict__ filt)
{
  const int b  = blockIdx.x / KK;
  const int kk = blockIdx.x - b * KK;
  const int c  = threadIdx.x;

  __shared__ float feat[C1];
  if (c < C1) {
    float s = 0.f;
#pragma unroll
    for (int ch = 0; ch < NCH; ++ch)
      s += partial[((size_t)b * NCH + ch) * C1 + c];
    feat[c] = s * (1.f / (H * W));
  }
  __syncthreads();

  const int idx = c * KK + kk;
  float v = bf[idx];
  const float* wr = wf + (size_t)idx * C1;
#pragma unroll
  for (int j = 0; j < C1; ++j) v += feat[j] * wr[j];
  v = (v - m2[idx]) * (g2[idx] * rsqrtf(v2[idx] + EPSV)) + be2[idx];

  __shared__ float red[256];
  red[c] = v;
  __syncthreads();
#pragma unroll
  for (int s = 128; s > 0; s >>= 1) {
    if (c < s) red[c] = fmaxf(red[c], red[c + s]);
    __syncthreads();
  }
  float mx = red[0];
  __syncthreads();
  float e = expf(v - mx);
  red[c] = e;
  __syncthreads();
#pragma unroll
  for (int s = 128; s > 0; s >>= 1) {
    if (c < s) red[c] += red[c + s];
    __syncthreads();
  }
  filt[((size_t)b * C + c) * FSTR + kk] = e / red[0];
}

// ---------------------------------------------------------------------------
// Kernel 3: per-sample dynamic depthwise 5x5 conv, reflect pad 2.
// High-occupancy small-tile design: 32-row x 128-col tile, 256 thr,
// __launch_bounds__(256,8) -> 8 blocks/CU (LDS 19.6 KB, VGPR <= 64).
// TW3=136 keeps every LDS row 16B-aligned (conflict-free ds_read_b128).
// Each thread: 4 output rows x 4 cols, 1.0 b128 read/px, NT f4 stores.
// Grid 16384, XCD swizzle keeps a plane's 4 tiles on one XCD (halo L2 hits).
// ---------------------------------------------------------------------------
#define R3  32
#define TW3 136             // 544 B row stride: 16B-aligned, conflict-free
#define TH3 (R3 + 4)        // 36 tile rows

__global__ __launch_bounds__(256, 8) void k3_dwconv(
    const float* __restrict__ x, const float* __restrict__ filt,
    float* __restrict__ out)
{
  const int bid = blockIdx.x;
  const int swz = (bid & 7) * 2048 + (bid >> 3);   // 16384 % 8 == 0, bijective
  const int plane = swz >> 2;                       // b*C + c
  const int tile  = swz & 3;
  const int r0    = tile * R3;
  const int tid   = threadIdx.x;

  const float* xp = x   + (size_t)plane * H * W;
  float*       op = out + (size_t)plane * H * W;
  const float* fp = filt + (size_t)plane * FSTR;

  f4 fv[7];
#pragma unroll
  for (int i = 0; i < 7; ++i) fv[i] = *(const f4*)&fp[i << 2];

  __shared__ __align__(16) float t[TH3][TW3];

  // interior staging: 36 rows x 32 f4-groups (input col c -> LDS col c+2)
#pragma unroll
  for (int k = 0; k < 5; ++k) {
    int idx = tid + (k << 8);
    if (k < 4 || idx < TH3 * 32) {
      int r = idx >> 5, g = idx & 31;
      int gr = r0 + r - 2;
      gr = gr < 0 ? -gr : (gr >= H ? 2 * H - 2 - gr : gr);
      f4 v = *(const f4*)&xp[gr * W + (g << 2)];
      f2 lo = {v[0], v[1]};
      f2 hi = {v[2], v[3]};
      *(f2*)&t[r][(g << 2) + 2] = lo;
      *(f2*)&t[r][(g << 2) + 4] = hi;
    }
  }
  // column halo: 36 rows x 4 cols (reflect cols)
  if (tid < TH3 * 4) {
    int r = tid >> 2, c = tid & 3;
    int cc = (c == 0) ? 0 : (c == 1) ? 1 : (c == 2) ? 130 : 131;
    int gc = (c == 0) ? 2 : (c == 1) ? 1 : (c == 2) ? 126 : 125;
    int gr = r0 + r - 2;
    gr = gr < 0 ? -gr : (gr >= H ? 2 * H - 2 - gr : gr);
    t[r][cc] = xp[gr * W + gc];
  }
  __syncthreads();

  const int w  = (tid & 31) << 2;          // output col group
  const int rb = (tid >> 5) << 2;          // output rows rb..rb+3 (in tile)
  f4 acc[4];
#pragma unroll
  for (int q = 0; q < 4; ++q) acc[q] = (f4){0.f, 0.f, 0.f, 0.f};

#pragma unroll
  for (int tr = 0; tr < 8; ++tr) {         // tap tile rows rb..rb+7
    f4 a  = *(const f4*)&t[rb + tr][w];
    f4 bb = *(const f4*)&t[rb + tr][w + 4];
#pragma unroll
    for (int q = 0; q < 4; ++q) {
      if (tr - q < 0 || tr - q > 4) continue;
      const int ki = tr - q;               // kernel row
#pragma unroll
      for (int p = 0; p < 4; ++p) {
#pragma unroll
        for (int j = 0; j < 5; ++j) {
          float e = (p + j < 4) ? a[p + j] : bb[p + j - 4];
          const int k = ki * 5 + j;
          acc[q][p] += e * fv[k >> 2][k & 3];
        }
      }
    }
  }
#pragma unroll
  for (int q = 0; q < 4; ++q)
    __builtin_nontemporal_store(acc[q], (f4*)&op[(r0 + rb + q) * W + w]);
}

// ---------------------------------------------------------------------------
extern "C" void kernel_launch(void* const* d_in, const int* in_sizes, int n_in,
                              void* d_out, int out_size, void* d_ws, size_t ws_size,
                              hipStream_t stream) {
  const float* x_feat = (const float*)d_in[0];
  const float* raw    = (const float*)d_in[1];
  const float* wconv  = (const float*)d_in[2];
  const float* bconv  = (const float*)d_in[3];
  const float* g1     = (const float*)d_in[4];
  const float* be1    = (const float*)d_in[5];
  const float* m1     = (const float*)d_in[6];
  const float* v1     = (const float*)d_in[7];
  const float* wf     = (const float*)d_in[8];
  const float* bf     = (const float*)d_in[9];
  const float* g2     = (const float*)d_in[10];
  const float* be2    = (const float*)d_in[11];
  const float* m2     = (const float*)d_in[12];
  const float* v2     = (const float*)d_in[13];
  float* out = (float*)d_out;

  float* partial = (float*)d_ws;                    // B*NCH*C1 floats
  float* filt    = partial + B * NCH * C1;          // B*C*FSTR floats

  k1_conv_pool<<<B * 16 * 4, 128, 0, stream>>>(raw, wconv, bconv, g1, be1, m1, v1, partial);
  k2_filter  <<<B * KK, 256, 0, stream>>>(partial, wf, bf, g2, be2, m2, v2, filt);
  k3_dwconv  <<<B * C * (H / R3), 256, 0, stream>>>(x_feat, filt, out);
}

// Round 7
// 124.311 us; speedup vs baseline: 5.8603x; 1.0219x over previous
//
#include <hip/hip_runtime.h>

#define EPSV 1e-5f

typedef float f4 __attribute__((ext_vector_type(4)));
typedef float f2 __attribute__((ext_vector_type(2)));

// Problem constants (match setup_inputs)
#define B   16
#define CIN 3
#define C1  64
#define C   256
#define H   128
#define W   128
#define K   5
#define KK  25
#define FSTR 28            // padded filter stride (16B-aligned f4 loads)

// ---------------------------------------------------------------------------
// Kernel 0: weight prep. blocks 0..99: transpose wf (6400x64) into
// wfT[j][kk][c] (k2 reads coalesced over c). block 100: wconvT[k][c] +
// folded BN constants Ag/Bg for k1.
// ---------------------------------------------------------------------------
__global__ __launch_bounds__(256) void k0_prep(
    const float* __restrict__ wconv, const float* __restrict__ bconv,
    const float* __restrict__ g1, const float* __restrict__ be1,
    const float* __restrict__ m1, const float* __restrict__ v1,
    const float* __restrict__ wf,
    float* __restrict__ wconvT, float* __restrict__ Ag,
    float* __restrict__ Bg, float* __restrict__ wfT)
{
  const int bid = blockIdx.x, tid = threadIdx.x;
  if (bid < 100) {
    const int kk = bid >> 2;          // 0..24
    const int c0 = (bid & 3) << 6;    // 0,64,128,192
    __shared__ float tl[64][65];
    for (int i = tid; i < 64 * 64; i += 256) {
      int cl = i >> 6, j = i & 63;    // read coalesced over j
      tl[cl][j] = wf[((size_t)(c0 + cl) * KK + kk) * C1 + j];
    }
    __syncthreads();
    for (int i = tid; i < 64 * 64; i += 256) {
      int j = i >> 6, cl = i & 63;    // write coalesced over c
      wfT[(size_t)j * (C * KK) + kk * C + c0 + cl] = tl[cl][j];
    }
  } else {
    for (int i = tid; i < 27 * 64; i += 256) {
      int k = i >> 6, c = i & 63;
      wconvT[k * 64 + c] = wconv[c * 27 + k];
    }
    if (tid < C1) {
      float sc = g1[tid] * rsqrtf(v1[tid] + EPSV);
      Ag[tid] = sc;
      Bg[tid] = (bconv[tid] - m1[tid]) * sc + be1[tid];
    }
  }
}

// ---------------------------------------------------------------------------
// Kernel 1: Conv2d(3->64,3x3,zero-pad 1) + folded bias/BN + ReLU -> partial
// sums for global avg pool. Grid 1024 blocks x 128 thr. Weights from wconvT
// (lane-coalesced), BN constants precomputed.
// ---------------------------------------------------------------------------
#define R1   8
#define WS1  32
#define TW1  36

__global__ __launch_bounds__(128) void k1_conv_pool(
    const float* __restrict__ raw, const float* __restrict__ wconvT,
    const float* __restrict__ Ag, const float* __restrict__ Bg,
    float* __restrict__ partial)
{
  const int bid   = blockIdx.x;
  const int b     = bid >> 6;
  const int chunk = (bid >> 2) & 15;
  const int wh    = bid & 3;
  const int tid   = threadIdx.x;

  __shared__ __align__(16) float t[CIN][R1 + 2][TW1];
  const float* rawb = raw + (size_t)b * CIN * H * W;
  for (int i = tid; i < CIN * (R1 + 2) * 34; i += 128) {
    int ic  = i / ((R1 + 2) * 34);
    int rem = i - ic * (R1 + 2) * 34;
    int r   = rem / 34;
    int cc  = rem - r * 34;
    int gr  = chunk * R1 + r - 1;
    int gc  = wh * WS1 + cc - 1;
    float val = 0.f;
    if ((unsigned)gr < H && (unsigned)gc < W)
      val = rawb[ic * H * W + gr * W + gc];
    t[ic][r][cc] = val;
  }
  __syncthreads();

  const int rp  = tid >> 5;
  const int grp = tid & 31;
  float wt[2][27], A[2], Bc[2];
#pragma unroll
  for (int k = 0; k < 27; ++k) {
    wt[0][k] = wconvT[k * 64 + grp * 2];
    wt[1][k] = wconvT[k * 64 + grp * 2 + 1];
  }
#pragma unroll
  for (int g = 0; g < 2; ++g) {
    A[g]  = Ag[grp * 2 + g];
    Bc[g] = Bg[grp * 2 + g];
  }

  f4 cur[CIN][4], nxt[CIN][4];
#pragma unroll
  for (int ic = 0; ic < CIN; ++ic)
#pragma unroll
    for (int r = 0; r < 4; ++r) cur[ic][r] = *(const f4*)&t[ic][2 * rp + r][0];

  float acc0 = 0.f, acc1 = 0.f;
#pragma unroll
  for (int j = 0; j < 8; ++j) {
#pragma unroll
    for (int ic = 0; ic < CIN; ++ic)
#pragma unroll
      for (int r = 0; r < 4; ++r) nxt[ic][r] = *(const f4*)&t[ic][2 * rp + r][4 * j + 4];

    float v[2][2][4];
#pragma unroll
    for (int q = 0; q < 2; ++q)
#pragma unroll
      for (int g = 0; g < 2; ++g)
#pragma unroll
        for (int p = 0; p < 4; ++p) v[q][g][p] = 0.f;

#pragma unroll
    for (int ic = 0; ic < CIN; ++ic) {
#pragma unroll
      for (int q = 0; q < 2; ++q) {
#pragma unroll
        for (int kh = 0; kh < 3; ++kh) {
          f4 a  = cur[ic][q + kh];
          f4 bb = nxt[ic][q + kh];
#pragma unroll
          for (int p = 0; p < 4; ++p) {
#pragma unroll
            for (int kw = 0; kw < 3; ++kw) {
              float e = (p + kw < 4) ? a[p + kw] : bb[p + kw - 4];
              v[q][0][p] += e * wt[0][ic * 9 + kh * 3 + kw];
              v[q][1][p] += e * wt[1][ic * 9 + kh * 3 + kw];
            }
          }
        }
      }
    }
#pragma unroll
    for (int q = 0; q < 2; ++q)
#pragma unroll
      for (int p = 0; p < 4; ++p) {
        acc0 += fmaxf(v[q][0][p] * A[0] + Bc[0], 0.f);
        acc1 += fmaxf(v[q][1][p] * A[1] + Bc[1], 0.f);
      }
#pragma unroll
    for (int ic = 0; ic < CIN; ++ic)
#pragma unroll
      for (int r = 0; r < 4; ++r) cur[ic][r] = nxt[ic][r];
  }

  __shared__ float red[4][C1];
  red[rp][grp * 2]     = acc0;
  red[rp][grp * 2 + 1] = acc1;
  __syncthreads();
  if (tid < C1) {
    float s = red[0][tid] + red[1][tid] + red[2][tid] + red[3][tid];
    partial[((size_t)((b * 16 + chunk) * 4 + wh)) * C1 + tid] = s;
  }
}

// ---------------------------------------------------------------------------
// Kernel 2: pool mean -> dense + BN -> softmax over C. wfT reads coalesced.
// ---------------------------------------------------------------------------
#define NCH 64

__global__ __launch_bounds__(256) void k2_filter(
    const float* __restrict__ partial, const float* __restrict__ wfT,
    const float* __restrict__ bf, const float* __restrict__ g2,
    const float* __restrict__ be2, const float* __restrict__ m2,
    const float* __restrict__ v2, float* __restrict__ filt)
{
  const int b  = blockIdx.x / KK;
  const int kk = blockIdx.x - b * KK;
  const int c  = threadIdx.x;

  __shared__ float feat[C1];
  if (c < C1) {
    float s = 0.f;
#pragma unroll
    for (int ch = 0; ch < NCH; ++ch)
      s += partial[((size_t)b * NCH + ch) * C1 + c];
    feat[c] = s * (1.f / (H * W));
  }
  __syncthreads();

  const int idx = c * KK + kk;
  float v = bf[idx];
#pragma unroll
  for (int j = 0; j < C1; ++j)
    v += feat[j] * wfT[(size_t)j * (C * KK) + kk * C + c];
  v = (v - m2[idx]) * (g2[idx] * rsqrtf(v2[idx] + EPSV)) + be2[idx];

  __shared__ float red[256];
  red[c] = v;
  __syncthreads();
#pragma unroll
  for (int s = 128; s > 0; s >>= 1) {
    if (c < s) red[c] = fmaxf(red[c], red[c + s]);
    __syncthreads();
  }
  float mx = red[0];
  __syncthreads();
  float e = expf(v - mx);
  red[c] = e;
  __syncthreads();
#pragma unroll
  for (int s = 128; s > 0; s >>= 1) {
    if (c < s) red[c] += red[c + s];
    __syncthreads();
  }
  filt[((size_t)b * C + c) * FSTR + kk] = e / red[0];
}

// ---------------------------------------------------------------------------
// Kernel 3: per-sample dynamic depthwise 5x5 conv, reflect pad 2.
// DMA-staged tile: LDS t[36][128] (512B rows), global_load_lds width-16
// stages 2 rows per wave-op (per-lane global addr does row reflect; lane 32
// lands on row+1). Column reflect via 4 cndmask selects per tap-row (edge
// lane g==31 outputs cols 126,127,0,1). f2 NT stores. 6 blocks/CU.
// ---------------------------------------------------------------------------
#define R3  32
#define TH3 36

__global__ __launch_bounds__(256, 6) void k3_dwconv(
    const float* __restrict__ x, const float* __restrict__ filt,
    float* __restrict__ out)
{
  const int bid = blockIdx.x;
  const int swz = (bid & 7) * 2048 + (bid >> 3);   // 16384 % 8 == 0, bijective
  const int plane = swz >> 2;                       // b*C + c
  const int tile  = swz & 3;
  const int r0    = tile * R3;
  const int tid   = threadIdx.x;
  const int lane  = tid & 63;
  const int wv    = tid >> 6;

  const float* xp = x   + (size_t)plane * H * W;
  float*       op = out + (size_t)plane * H * W;
  const float* fp = filt + (size_t)plane * FSTR;

  f4 fv[7];
#pragma unroll
  for (int i = 0; i < 7; ++i) fv[i] = *(const f4*)&fp[i << 2];

  __shared__ __align__(16) float t[TH3][W];

  // staging: op i stages tile rows 2i,2i+1 (wave-uniform LDS base &t[2i][0];
  // lane l writes bytes 16l -> lanes 32..63 land on row 2i+1). 18 ops.
  for (int i = wv; i < TH3 / 2; i += 4) {
    int r  = 2 * i + (lane >> 5);
    int gr = r0 + r - 2;
    gr = gr < 0 ? -gr : (gr >= H ? 2 * H - 2 - gr : gr);
    const float* gsrc = xp + gr * W + ((lane & 31) << 2);
    __builtin_amdgcn_global_load_lds(
        (const __attribute__((address_space(1))) void*)gsrc,
        (__attribute__((address_space(3))) void*)&t[2 * i][0],
        16, 0, 0);
  }
  __syncthreads();

  const int g    = tid & 31;
  const int w    = g << 2;
  const bool edge = (g == 31);
  const int bcol = edge ? 0   : w + 4;   // edge b-load wraps to cols 0..3
  const int colA = edge ? 126 : w + 2;   // f2 store (outputs from wa)
  const int colB = edge ? 0   : w + 4;   // f2 store (outputs from wb)
  const int rb   = (tid >> 5) << 2;      // output rows rb..rb+3 (in tile)

  f4 acc[4];
#pragma unroll
  for (int q = 0; q < 4; ++q) acc[q] = (f4){0.f, 0.f, 0.f, 0.f};

#pragma unroll
  for (int tr = 0; tr < 8; ++tr) {       // tap tile rows rb..rb+7
    f4 a  = *(const f4*)&t[rb + tr][w];
    f4 bb = *(const f4*)&t[rb + tr][bcol];
    float wa[6], wb[6];
    wa[0] = a[0]; wa[1] = a[1]; wa[2] = a[2]; wa[3] = a[3];
    wa[4] = edge ? a[2]  : bb[0];
    wa[5] = edge ? a[1]  : bb[1];
    wb[0] = edge ? bb[2] : a[2];
    wb[1] = edge ? bb[1] : a[3];
    wb[2] = bb[0]; wb[3] = bb[1]; wb[4] = bb[2]; wb[5] = bb[3];
#pragma unroll
    for (int q = 0; q < 4; ++q) {
      if (tr - q < 0 || tr - q > 4) continue;
      const int ki = tr - q;             // kernel row
#pragma unroll
      for (int j = 0; j < 5; ++j) {
        const int kq = ki * 5 + j;
        const float fk = fv[kq >> 2][kq & 3];
        acc[q][0] += wa[j]     * fk;
        acc[q][1] += wa[j + 1] * fk;
        acc[q][2] += wb[j]     * fk;
        acc[q][3] += wb[j + 1] * fk;
      }
    }
  }
#pragma unroll
  for (int q = 0; q < 4; ++q) {
    const int row = r0 + rb + q;
    f2 vA = {acc[q][0], acc[q][1]};
    f2 vB = {acc[q][2], acc[q][3]};
    __builtin_nontemporal_store(vA, (f2*)&op[row * W + colA]);
    __builtin_nontemporal_store(vB, (f2*)&op[row * W + colB]);
  }
}

// ---------------------------------------------------------------------------
extern "C" void kernel_launch(void* const* d_in, const int* in_sizes, int n_in,
                              void* d_out, int out_size, void* d_ws, size_t ws_size,
                              hipStream_t stream) {
  const float* x_feat = (const float*)d_in[0];
  const float* raw    = (const float*)d_in[1];
  const float* wconv  = (const float*)d_in[2];
  const float* bconv  = (const float*)d_in[3];
  const float* g1     = (const float*)d_in[4];
  const float* be1    = (const float*)d_in[5];
  const float* m1     = (const float*)d_in[6];
  const float* v1     = (const float*)d_in[7];
  const float* wf     = (const float*)d_in[8];
  const float* bf     = (const float*)d_in[9];
  const float* g2     = (const float*)d_in[10];
  const float* be2    = (const float*)d_in[11];
  const float* m2     = (const float*)d_in[12];
  const float* v2     = (const float*)d_in[13];
  float* out = (float*)d_out;

  float* partial = (float*)d_ws;                    // 16*64*64      = 65536
  float* filt    = partial + B * NCH * C1;          // 16*256*28     = 114688
  float* wconvT  = filt + B * C * FSTR;             // 27*64         = 1728
  float* Ag      = wconvT + 27 * 64;                // 64
  float* Bg      = Ag + 64;                         // 64
  float* wfT     = Bg + 64;                         // 64*25*256     = 409600

  k0_prep    <<<101, 256, 0, stream>>>(wconv, bconv, g1, be1, m1, v1, wf,
                                       wconvT, Ag, Bg, wfT);
  k1_conv_pool<<<B * 16 * 4, 128, 0, stream>>>(raw, wconvT, Ag, Bg, partial);
  k2_filter  <<<B * KK, 256, 0, stream>>>(partial, wfT, bf, g2, be2, m2, v2, filt);
  k3_dwconv  <<<B * C * (H / R3), 256, 0, stream>>>(x_feat, filt, out);
}